// Round 2
// baseline (231.465 us; speedup 1.0000x reference)
//
#include <hip/hip_runtime.h>
#include <cstdint>

// DirectAU loss: align(u,i) + 0.5*(uniform(u) + uniform(i)), T=2, GAMMA=1.
// N=8192 rows, D=64. Strategy:
//   k1: normalize rows (fp32), write bf16 copies to ws, accumulate alignment.
//   k2: tiled X@X^T via mfma_f32_16x16x32_bf16, fused exp2+sum epilogue,
//       upper-triangle blocks only (weight 2 off-diagonal). Layout-agnostic:
//       we only ever SUM the C-fragment elements, so the C/D lane mapping
//       cannot introduce a transpose bug.
//   k3: combine scalars -> d_out[0].
// Diagonal of exp-matrix is subtracted as exactly n (matches reference; bf16
// perturbation of diag is <2e-5 relative in the log).
// R1 resubmit: R0 bench died with "container failed twice" (infra, no pytest
// output). Kernel audited: no OOB, no capture-illegal calls, no hang paths.

#define NROWS 8192
#define DIM 64

static constexpr float EXP_SCALE = 5.770780163555852f; // 2*T*log2(e) = 4*log2(e)
static constexpr float EPS_F = 1e-8f;

typedef __bf16 bf16x8 __attribute__((ext_vector_type(8)));
typedef float f32x4 __attribute__((ext_vector_type(4)));

__device__ __forceinline__ unsigned short f32_to_bf16_rn(float f) {
    union { float f; uint32_t u; } c; c.f = f;
    uint32_t u = c.u;
    uint32_t r = u + 0x7FFFu + ((u >> 16) & 1u);
    return (unsigned short)(r >> 16);
}

// ---- kernel 1: normalize + bf16 cast + alignment sum -----------------------
__global__ void __launch_bounds__(256) normalize_align_kernel(
    const float* __restrict__ user, const float* __restrict__ item,
    unsigned short* __restrict__ xu, unsigned short* __restrict__ xi,
    float* __restrict__ acc)
{
    const int wave = threadIdx.x >> 6;
    const int lane = threadIdx.x & 63;
    const int row  = blockIdx.x * 4 + wave;   // one wave per row, D==64==wave
    const int idx  = row * DIM + lane;

    float u = user[idx];
    float v = item[idx];

    float su = u * u, sv = v * v;
    #pragma unroll
    for (int m = 1; m < 64; m <<= 1) {
        su += __shfl_xor(su, m, 64);
        sv += __shfl_xor(sv, m, 64);
    }
    // rsqrt + one Newton step (~fp32 accuracy)
    float iu = rsqrtf(su); iu = iu * (1.5f - 0.5f * su * iu * iu);
    float iv = rsqrtf(sv); iv = iv * (1.5f - 0.5f * sv * iv * iv);

    float un = u * iu, vn = v * iv;
    xu[idx] = f32_to_bf16_rn(un);
    xi[idx] = f32_to_bf16_rn(vn);

    float d = un - vn;
    float a = d * d;
    #pragma unroll
    for (int m = 1; m < 64; m <<= 1) a += __shfl_xor(a, m, 64);
    if (lane == 0) atomicAdd(&acc[0], a);
}

// ---- kernel 2: gram + exp + sum (one matrix per blockIdx.z) ----------------
// 128x128 C-tile per block; 4 waves, each wave does 2 row-blocks x 8 col-blocks
// of 16x16x32 MFMAs (K=64 -> 2 k-steps). Fragments loaded straight from
// global (L2-resident, 2 MB total). Only bi<=bj blocks do work.
__global__ void __launch_bounds__(256) gram_exp_kernel(
    const unsigned short* __restrict__ xu,
    const unsigned short* __restrict__ xi,
    float* __restrict__ acc)
{
    const int bi = blockIdx.x, bj = blockIdx.y;
    if (bj < bi) return;   // symmetry: upper triangle of blocks only

    const unsigned short* __restrict__ X = blockIdx.z ? xi : xu;
    float* dst = &acc[1 + blockIdx.z];

    const int wave = threadIdx.x >> 6;
    const int lane = threadIdx.x & 63;
    const int r16  = lane & 15;            // row-in-16 for both A and B frags
    const int koff = (lane >> 4) * 8;      // 8 contiguous bf16 per lane

    const int rowbase = bi * 128 + wave * 32;
    const int colbase = bj * 128;

    // Preload A fragments: 2 row-blocks x 2 k-steps (reused over 8 col-blocks)
    bf16x8 a[2][2];
    #pragma unroll
    for (int rb = 0; rb < 2; ++rb)
        #pragma unroll
        for (int ks = 0; ks < 2; ++ks)
            a[rb][ks] = *reinterpret_cast<const bf16x8*>(
                X + (rowbase + rb * 16 + r16) * DIM + koff + ks * 32);

    float local = 0.0f;
    #pragma unroll
    for (int cb = 0; cb < 8; ++cb) {
        const unsigned short* bp = X + (colbase + cb * 16 + r16) * DIM + koff;
        bf16x8 b0 = *reinterpret_cast<const bf16x8*>(bp);
        bf16x8 b1 = *reinterpret_cast<const bf16x8*>(bp + 32);
        #pragma unroll
        for (int rb = 0; rb < 2; ++rb) {
            f32x4 c = {0.f, 0.f, 0.f, 0.f};
            c = __builtin_amdgcn_mfma_f32_16x16x32_bf16(a[rb][0], b0, c, 0, 0, 0);
            c = __builtin_amdgcn_mfma_f32_16x16x32_bf16(a[rb][1], b1, c, 0, 0, 0);
            // epilogue: exp(-T*max(2-2g,0)) = exp2(min(g-1,0)*EXP_SCALE)
            #pragma unroll
            for (int e = 0; e < 4; ++e) {
                float s = fminf(c[e] - 1.0f, 0.0f);
                local += exp2f(s * EXP_SCALE);
            }
        }
    }

    // block reduction -> one atomic
    #pragma unroll
    for (int m = 1; m < 64; m <<= 1) local += __shfl_xor(local, m, 64);
    __shared__ float wsum[4];
    if (lane == 0) wsum[wave] = local;
    __syncthreads();
    if (threadIdx.x == 0) {
        float w = (bi == bj) ? 1.0f : 2.0f;
        atomicAdd(dst, (wsum[0] + wsum[1] + wsum[2] + wsum[3]) * w);
    }
}

// ---- kernel 3: final combine ----------------------------------------------
__global__ void final_kernel(const float* __restrict__ acc, float* __restrict__ out)
{
    const float n = (float)NROWS;
    float align = acc[0] / n;
    float denom = n * (n - 1.0f);
    float mu = (acc[1] - n) / denom;   // subtract diagonal (== n in reference)
    float mi = (acc[2] - n) / denom;
    out[0] = align + 0.5f * (logf(mu + EPS_F) + logf(mi + EPS_F));
}

extern "C" void kernel_launch(void* const* d_in, const int* in_sizes, int n_in,
                              void* d_out, int out_size, void* d_ws, size_t ws_size,
                              hipStream_t stream)
{
    const float* user = (const float*)d_in[0];
    const float* item = (const float*)d_in[1];

    unsigned short* xu = (unsigned short*)d_ws;                 // 1 MB
    unsigned short* xi = xu + (size_t)NROWS * DIM;              // 1 MB
    float* acc = (float*)(xi + (size_t)NROWS * DIM);            // 16 B
    // acc[0]=align_sum, acc[1]=sum_u(full sym), acc[2]=sum_i

    hipMemsetAsync(acc, 0, 4 * sizeof(float), stream);
    normalize_align_kernel<<<NROWS / 4, 256, 0, stream>>>(user, item, xu, xi, acc);
    gram_exp_kernel<<<dim3(64, 64, 2), 256, 0, stream>>>(xu, xi, acc);
    final_kernel<<<1, 1, 0, stream>>>(acc, (float*)d_out);
}

// Round 3
// 105.438 us; speedup vs baseline: 2.1953x; 2.1953x over previous
//
#include <hip/hip_runtime.h>
#include <cstdint>

// DirectAU loss: align(u,i) + 0.5*(uniform(u) + uniform(i)), T=2, GAMMA=1.
// N=8192 rows, D=64.
//   k1: normalize rows (fp32), write bf16 copies to ws, per-block align partial.
//   k2: tiled X@X^T via mfma_f32_16x16x32_bf16, fused exp2+sum epilogue,
//       per-block partial to ws slot. Upper-triangle tiles only, weight 2
//       off-diagonal; lower-triangle grid slots serve the ITEM matrix so
//       every block does work. Layout-agnostic: we only SUM C-fragment elems.
//   k3: reduce partials + combine -> d_out[0].
// R3: removed ALL atomics. R2 counters showed normalize at 107 us with
// VALUBusy 1% / HBM 0.3% — 8192 same-address atomicAdds serialized across
// XCDs. Partial-sum slots + single reduce kernel instead. Also removed the
// memset dispatch and the 48% dead blocks in the gram grid.

#define NROWS 8192
#define DIM 64
#define NTILE 64                     // 8192 / 128 tiles per side
#define GRAM_SLOTS (NTILE * (NTILE + 1))   // 64*65 = 4160, all live
#define K1_BLOCKS 512                // 4 waves/block * 4 rows/wave

static constexpr float EXP_SCALE = 5.770780163555852f; // 2*T*log2(e) = 4*log2(e)
static constexpr float EPS_F = 1e-8f;

typedef __bf16 bf16x8 __attribute__((ext_vector_type(8)));
typedef float f32x4 __attribute__((ext_vector_type(4)));

__device__ __forceinline__ unsigned short f32_to_bf16_rn(float f) {
    union { float f; uint32_t u; } c; c.f = f;
    uint32_t u = c.u;
    uint32_t r = u + 0x7FFFu + ((u >> 16) & 1u);
    return (unsigned short)(r >> 16);
}

// ---- kernel 1: normalize + bf16 cast + per-block alignment partial ---------
__global__ void __launch_bounds__(256) normalize_align_kernel(
    const float* __restrict__ user, const float* __restrict__ item,
    unsigned short* __restrict__ xu, unsigned short* __restrict__ xi,
    float* __restrict__ pa)
{
    const int wave = threadIdx.x >> 6;
    const int lane = threadIdx.x & 63;
    const int wid  = blockIdx.x * 4 + wave;   // 0..2047, 4 rows per wave

    float asum = 0.0f;
    #pragma unroll
    for (int r = 0; r < 4; ++r) {
        const int idx = (wid * 4 + r) * DIM + lane;   // wave spans one row
        float u = user[idx];
        float v = item[idx];
        float su = u * u, sv = v * v;
        #pragma unroll
        for (int m = 1; m < 64; m <<= 1) {
            su += __shfl_xor(su, m, 64);
            sv += __shfl_xor(sv, m, 64);
        }
        float iu = rsqrtf(su); iu = iu * (1.5f - 0.5f * su * iu * iu);
        float iv = rsqrtf(sv); iv = iv * (1.5f - 0.5f * sv * iv * iv);
        float un = u * iu, vn = v * iv;
        xu[idx] = f32_to_bf16_rn(un);
        xi[idx] = f32_to_bf16_rn(vn);
        float d = un - vn;
        asum += d * d;
    }
    #pragma unroll
    for (int m = 1; m < 64; m <<= 1) asum += __shfl_xor(asum, m, 64);
    __shared__ float ws4[4];
    if (lane == 0) ws4[wave] = asum;
    __syncthreads();
    if (threadIdx.x == 0) pa[blockIdx.x] = ws4[0] + ws4[1] + ws4[2] + ws4[3];
}

// ---- kernel 2: gram + exp + per-block partial ------------------------------
// Grid (64, 65). by<64 && by>=bx -> USER tile (bi=bx,bj=by);
// by<64 && by<bx  -> ITEM strict-upper tile (bi=by,bj=bx);
// by==64          -> ITEM diagonal tile (bi=bj=bx).  All 4160 blocks live.
__global__ void __launch_bounds__(256) gram_exp_kernel(
    const unsigned short* __restrict__ xu,
    const unsigned short* __restrict__ xi,
    float* __restrict__ pg)
{
    const int bx = blockIdx.x, by = blockIdx.y;
    const unsigned short* __restrict__ X;
    int bi, bj;
    if (by < NTILE) {
        if (by >= bx) { X = xu; bi = bx; bj = by; }
        else          { X = xi; bi = by; bj = bx; }
    } else            { X = xi; bi = bx; bj = bx; }

    const int wave = threadIdx.x >> 6;
    const int lane = threadIdx.x & 63;
    const int r16  = lane & 15;            // row-in-16 for both A and B frags
    const int koff = (lane >> 4) * 8;      // 8 contiguous bf16 per lane

    const int rowbase = bi * 128 + wave * 32;
    const int colbase = bj * 128;

    // Preload A fragments: 2 row-blocks x 2 k-steps (reused over 8 col-blocks)
    bf16x8 a[2][2];
    #pragma unroll
    for (int rb = 0; rb < 2; ++rb)
        #pragma unroll
        for (int ks = 0; ks < 2; ++ks)
            a[rb][ks] = *reinterpret_cast<const bf16x8*>(
                X + (rowbase + rb * 16 + r16) * DIM + koff + ks * 32);

    float local = 0.0f;
    #pragma unroll
    for (int cb = 0; cb < 8; ++cb) {
        const unsigned short* bp = X + (colbase + cb * 16 + r16) * DIM + koff;
        bf16x8 b0 = *reinterpret_cast<const bf16x8*>(bp);
        bf16x8 b1 = *reinterpret_cast<const bf16x8*>(bp + 32);
        #pragma unroll
        for (int rb = 0; rb < 2; ++rb) {
            f32x4 c = {0.f, 0.f, 0.f, 0.f};
            c = __builtin_amdgcn_mfma_f32_16x16x32_bf16(a[rb][0], b0, c, 0, 0, 0);
            c = __builtin_amdgcn_mfma_f32_16x16x32_bf16(a[rb][1], b1, c, 0, 0, 0);
            // epilogue: exp(-T*max(2-2g,0)) = exp2(min(g-1,0)*EXP_SCALE)
            #pragma unroll
            for (int e = 0; e < 4; ++e) {
                float s = fminf(c[e] - 1.0f, 0.0f);
                local += exp2f(s * EXP_SCALE);
            }
        }
    }

    #pragma unroll
    for (int m = 1; m < 64; m <<= 1) local += __shfl_xor(local, m, 64);
    __shared__ float wsum[4];
    if (lane == 0) wsum[wave] = local;
    __syncthreads();
    if (threadIdx.x == 0) {
        float w = (bi == bj) ? 1.0f : 2.0f;
        pg[by * NTILE + bx] = (wsum[0] + wsum[1] + wsum[2] + wsum[3]) * w;
    }
}

// ---- kernel 3: reduce partials + combine -----------------------------------
__global__ void __launch_bounds__(256) final_kernel(
    const float* __restrict__ pa, const float* __restrict__ pg,
    float* __restrict__ out)
{
    float a = 0.f, su = 0.f, si = 0.f;
    for (int s = threadIdx.x; s < K1_BLOCKS; s += 256) a += pa[s];
    for (int s = threadIdx.x; s < GRAM_SLOTS; s += 256) {
        int bx = s & (NTILE - 1), by = s >> 6;
        bool is_item = (by == NTILE) || (by < bx);
        float v = pg[s];
        if (is_item) si += v; else su += v;
    }
    #pragma unroll
    for (int m = 1; m < 64; m <<= 1) {
        a  += __shfl_xor(a,  m, 64);
        su += __shfl_xor(su, m, 64);
        si += __shfl_xor(si, m, 64);
    }
    __shared__ float r[12];
    const int wave = threadIdx.x >> 6, lane = threadIdx.x & 63;
    if (lane == 0) { r[wave] = a; r[4 + wave] = su; r[8 + wave] = si; }
    __syncthreads();
    if (threadIdx.x == 0) {
        float A  = r[0] + r[1] + r[2]  + r[3];
        float SU = r[4] + r[5] + r[6]  + r[7];
        float SI = r[8] + r[9] + r[10] + r[11];
        const float n = (float)NROWS;
        const float denom = n * (n - 1.0f);
        out[0] = A / n + 0.5f * (logf((SU - n) / denom + EPS_F)
                               + logf((SI - n) / denom + EPS_F));
    }
}

extern "C" void kernel_launch(void* const* d_in, const int* in_sizes, int n_in,
                              void* d_out, int out_size, void* d_ws, size_t ws_size,
                              hipStream_t stream)
{
    const float* user = (const float*)d_in[0];
    const float* item = (const float*)d_in[1];

    unsigned short* xu = (unsigned short*)d_ws;                 // 1 MB
    unsigned short* xi = xu + (size_t)NROWS * DIM;              // 1 MB
    float* pa = (float*)(xi + (size_t)NROWS * DIM);             // 512 floats
    float* pg = pa + K1_BLOCKS;                                 // 4160 floats

    normalize_align_kernel<<<K1_BLOCKS, 256, 0, stream>>>(user, item, xu, xi, pa);
    gram_exp_kernel<<<dim3(NTILE, NTILE + 1), 256, 0, stream>>>(xu, xi, pg);
    final_kernel<<<1, 256, 0, stream>>>(pa, pg, (float*)d_out);
}

// Round 4
// 104.558 us; speedup vs baseline: 2.2138x; 1.0084x over previous
//
#include <hip/hip_runtime.h>
#include <cstdint>

// DirectAU loss: align(u,i) + 0.5*(uniform(u) + uniform(i)), T=2, GAMMA=1.
// N=8192 rows, D=64.
//   k1: normalize rows (fp32), write bf16 copies to ws, per-block align partial.
//   k2: tiled X@X^T via mfma_f32_16x16x32_bf16, fused exp2+sum epilogue,
//       per-block partial to ws slot. Upper-triangle tiles only, weight 2
//       off-diagonal; lower-triangle grid slots serve the ITEM matrix.
//   k3: reduce partials + combine -> d_out[0].
// R4: R3 gram was 44.7us, VALUBusy 47% / MfmaUtil 7% -> VALU-issue bound at
// ~3.5x the modeled instruction count. Cause: exp2f() lowers to the OCML
// precise path (~10+ insts), not v_exp_f32. Fix: __builtin_amdgcn_exp2f +
// 3-inst epilogue (fma,exp,add); clamp-to-1 only on diagonal blocks where
// g>1 is possible (exact for off-diag: max g ~0.7 for this data).

#define NROWS 8192
#define DIM 64
#define NTILE 64                           // 8192 / 128 tiles per side
#define GRAM_SLOTS (NTILE * (NTILE + 1))   // 64*65 = 4160, all live
#define K1_BLOCKS 512                      // 4 waves/block * 4 rows/wave

static constexpr float EXP_SCALE = 5.770780163555852f; // 2*T*log2(e) = 4*log2(e)
static constexpr float EPS_F = 1e-8f;

typedef __bf16 bf16x8 __attribute__((ext_vector_type(8)));
typedef float f32x4 __attribute__((ext_vector_type(4)));

__device__ __forceinline__ unsigned short f32_to_bf16_rn(float f) {
    union { float f; uint32_t u; } c; c.f = f;
    uint32_t u = c.u;
    uint32_t r = u + 0x7FFFu + ((u >> 16) & 1u);
    return (unsigned short)(r >> 16);
}

// ---- kernel 1: normalize + bf16 cast + per-block alignment partial ---------
__global__ void __launch_bounds__(256) normalize_align_kernel(
    const float* __restrict__ user, const float* __restrict__ item,
    unsigned short* __restrict__ xu, unsigned short* __restrict__ xi,
    float* __restrict__ pa)
{
    const int wave = threadIdx.x >> 6;
    const int lane = threadIdx.x & 63;
    const int wid  = blockIdx.x * 4 + wave;   // 0..2047, 4 rows per wave

    float asum = 0.0f;
    #pragma unroll
    for (int r = 0; r < 4; ++r) {
        const int idx = (wid * 4 + r) * DIM + lane;   // wave spans one row
        float u = user[idx];
        float v = item[idx];
        float su = u * u, sv = v * v;
        #pragma unroll
        for (int m = 1; m < 64; m <<= 1) {
            su += __shfl_xor(su, m, 64);
            sv += __shfl_xor(sv, m, 64);
        }
        float iu = rsqrtf(su); iu = iu * (1.5f - 0.5f * su * iu * iu);
        float iv = rsqrtf(sv); iv = iv * (1.5f - 0.5f * sv * iv * iv);
        float un = u * iu, vn = v * iv;
        xu[idx] = f32_to_bf16_rn(un);
        xi[idx] = f32_to_bf16_rn(vn);
        float d = un - vn;
        asum += d * d;
    }
    #pragma unroll
    for (int m = 1; m < 64; m <<= 1) asum += __shfl_xor(asum, m, 64);
    __shared__ float ws4[4];
    if (lane == 0) ws4[wave] = asum;
    __syncthreads();
    if (threadIdx.x == 0) pa[blockIdx.x] = ws4[0] + ws4[1] + ws4[2] + ws4[3];
}

// ---- kernel 2: gram + exp + per-block partial ------------------------------
// Grid (64, 65). by<64 && by>=bx -> USER tile (bi=bx,bj=by);
// by<64 && by<bx  -> ITEM strict-upper tile (bi=by,bj=bx);
// by==64          -> ITEM diagonal tile (bi=bj=bx).  All 4160 blocks live.
template<bool DIAG>
__device__ __forceinline__ float gram_tile_sum(
    const unsigned short* __restrict__ X, int bi, int bj, int wave, int lane)
{
    const int r16  = lane & 15;            // row-in-16 for both A and B frags
    const int koff = (lane >> 4) * 8;      // 8 contiguous bf16 per lane

    const int rowbase = bi * 128 + wave * 32;
    const int colbase = bj * 128;

    // Preload A fragments: 2 row-blocks x 2 k-steps (reused over 8 col-blocks)
    bf16x8 a[2][2];
    #pragma unroll
    for (int rb = 0; rb < 2; ++rb)
        #pragma unroll
        for (int ks = 0; ks < 2; ++ks)
            a[rb][ks] = *reinterpret_cast<const bf16x8*>(
                X + (rowbase + rb * 16 + r16) * DIM + koff + ks * 32);

    float local = 0.0f;
    #pragma unroll
    for (int cb = 0; cb < 8; ++cb) {
        const unsigned short* bp = X + (colbase + cb * 16 + r16) * DIM + koff;
        bf16x8 b0 = *reinterpret_cast<const bf16x8*>(bp);
        bf16x8 b1 = *reinterpret_cast<const bf16x8*>(bp + 32);
        #pragma unroll
        for (int rb = 0; rb < 2; ++rb) {
            f32x4 c = {0.f, 0.f, 0.f, 0.f};
            c = __builtin_amdgcn_mfma_f32_16x16x32_bf16(a[rb][0], b0, c, 0, 0, 0);
            c = __builtin_amdgcn_mfma_f32_16x16x32_bf16(a[rb][1], b1, c, 0, 0, 0);
            // exp(-T*max(2-2g,0)) = min(exp2(g*S - S), 1); clamp only where
            // g>1 is possible (diagonal blocks).
            #pragma unroll
            for (int e = 0; e < 4; ++e) {
                float ex = __builtin_amdgcn_exp2f(fmaf(c[e], EXP_SCALE, -EXP_SCALE));
                if (DIAG) ex = fminf(ex, 1.0f);
                local += ex;
            }
        }
    }
    return local;
}

__global__ void __launch_bounds__(256) gram_exp_kernel(
    const unsigned short* __restrict__ xu,
    const unsigned short* __restrict__ xi,
    float* __restrict__ pg)
{
    const int bx = blockIdx.x, by = blockIdx.y;
    const unsigned short* __restrict__ X;
    int bi, bj;
    if (by < NTILE) {
        if (by >= bx) { X = xu; bi = bx; bj = by; }
        else          { X = xi; bi = by; bj = bx; }
    } else            { X = xi; bi = bx; bj = bx; }

    const int wave = threadIdx.x >> 6;
    const int lane = threadIdx.x & 63;

    float local = (bi == bj) ? gram_tile_sum<true >(X, bi, bj, wave, lane)
                             : gram_tile_sum<false>(X, bi, bj, wave, lane);

    #pragma unroll
    for (int m = 1; m < 64; m <<= 1) local += __shfl_xor(local, m, 64);
    __shared__ float wsum[4];
    if (lane == 0) wsum[wave] = local;
    __syncthreads();
    if (threadIdx.x == 0) {
        float w = (bi == bj) ? 1.0f : 2.0f;
        pg[by * NTILE + bx] = (wsum[0] + wsum[1] + wsum[2] + wsum[3]) * w;
    }
}

// ---- kernel 3: reduce partials + combine -----------------------------------
__global__ void __launch_bounds__(256) final_kernel(
    const float* __restrict__ pa, const float* __restrict__ pg,
    float* __restrict__ out)
{
    float a = 0.f, su = 0.f, si = 0.f;
    for (int s = threadIdx.x; s < K1_BLOCKS; s += 256) a += pa[s];
    for (int s = threadIdx.x; s < GRAM_SLOTS; s += 256) {
        int bx = s & (NTILE - 1), by = s >> 6;
        bool is_item = (by == NTILE) || (by < bx);
        float v = pg[s];
        if (is_item) si += v; else su += v;
    }
    #pragma unroll
    for (int m = 1; m < 64; m <<= 1) {
        a  += __shfl_xor(a,  m, 64);
        su += __shfl_xor(su, m, 64);
        si += __shfl_xor(si, m, 64);
    }
    __shared__ float r[12];
    const int wave = threadIdx.x >> 6, lane = threadIdx.x & 63;
    if (lane == 0) { r[wave] = a; r[4 + wave] = su; r[8 + wave] = si; }
    __syncthreads();
    if (threadIdx.x == 0) {
        float A  = r[0] + r[1] + r[2]  + r[3];
        float SU = r[4] + r[5] + r[6]  + r[7];
        float SI = r[8] + r[9] + r[10] + r[11];
        const float n = (float)NROWS;
        const float denom = n * (n - 1.0f);
        out[0] = A / n + 0.5f * (logf((SU - n) / denom + EPS_F)
                               + logf((SI - n) / denom + EPS_F));
    }
}

extern "C" void kernel_launch(void* const* d_in, const int* in_sizes, int n_in,
                              void* d_out, int out_size, void* d_ws, size_t ws_size,
                              hipStream_t stream)
{
    const float* user = (const float*)d_in[0];
    const float* item = (const float*)d_in[1];

    unsigned short* xu = (unsigned short*)d_ws;                 // 1 MB
    unsigned short* xi = xu + (size_t)NROWS * DIM;              // 1 MB
    float* pa = (float*)(xi + (size_t)NROWS * DIM);             // 512 floats
    float* pg = pa + K1_BLOCKS;                                 // 4160 floats

    normalize_align_kernel<<<K1_BLOCKS, 256, 0, stream>>>(user, item, xu, xi, pa);
    gram_exp_kernel<<<dim3(NTILE, NTILE + 1), 256, 0, stream>>>(xu, xi, pg);
    final_kernel<<<1, 256, 0, stream>>>(pa, pg, (float*)d_out);
}

// Round 5
// 87.477 us; speedup vs baseline: 2.6460x; 1.1953x over previous
//
#include <hip/hip_runtime.h>
#include <cstdint>

// DirectAU loss: align(u,i) + 0.5*(uniform(u) + uniform(i)), T=2, GAMMA=1.
// N=8192 rows, D=64.
//   k1: normalize rows (fp32), write bf16 copies to ws, per-block align partial.
//   k2: 256x256-tile X@X^T via mfma_f32_16x16x32_bf16 with LDS-staged stripes
//       in FRAGMENT-ORDER layout (all operand reads are contiguous
//       ds_read_b128 at base+lane*16), fused exp2+sum epilogue, per-block
//       partial. Upper-triangle tiles, weight 2 off-diag; lower-triangle grid
//       slots serve the ITEM matrix; extra column = item diagonals.
//   k3: reduce partials + combine -> d_out[0].
// R5: R4 falsified "VALU-bound" — exp fix halved VALUBusy (47->23%) but dur
// stayed 42.5us. Invariant: FETCH 7.8MB @ ~190GB/s, all pipes idle -> gram is
// L2-miss-latency bound (L2 cold each launch; per-lane fragment loads = 64B
// scattered segments, low MLP). Fix: 4x fewer/bigger tiles (256^2), bulk
// coalesced staging (1KB/instr streaming) into LDS, zero global loads in the
// MFMA loop.

#define NROWS 8192
#define DIM 64
#define NT2 32                            // 8192/256 tiles per side
#define GRAM_SLOTS (NT2 * (NT2 + 1))      // 32*33 = 1056
#define K1_BLOCKS 512                     // 4 waves/block * 4 rows/wave

static constexpr float EXP_SCALE = 5.770780163555852f; // 2*T*log2(e) = 4*log2(e)
static constexpr float EPS_F = 1e-8f;

typedef __bf16 bf16x8 __attribute__((ext_vector_type(8)));
typedef float f32x4 __attribute__((ext_vector_type(4)));

__device__ __forceinline__ unsigned short f32_to_bf16_rn(float f) {
    union { float f; uint32_t u; } c; c.f = f;
    uint32_t u = c.u;
    uint32_t r = u + 0x7FFFu + ((u >> 16) & 1u);
    return (unsigned short)(r >> 16);
}

// ---- kernel 1: normalize + bf16 cast + per-block alignment partial ---------
__global__ void __launch_bounds__(256) normalize_align_kernel(
    const float* __restrict__ user, const float* __restrict__ item,
    unsigned short* __restrict__ xu, unsigned short* __restrict__ xi,
    float* __restrict__ pa)
{
    const int wave = threadIdx.x >> 6;
    const int lane = threadIdx.x & 63;
    const int wid  = blockIdx.x * 4 + wave;   // 0..2047, 4 rows per wave

    float asum = 0.0f;
    #pragma unroll
    for (int r = 0; r < 4; ++r) {
        const int idx = (wid * 4 + r) * DIM + lane;   // wave spans one row
        float u = user[idx];
        float v = item[idx];
        float su = u * u, sv = v * v;
        #pragma unroll
        for (int m = 1; m < 64; m <<= 1) {
            su += __shfl_xor(su, m, 64);
            sv += __shfl_xor(sv, m, 64);
        }
        float iu = rsqrtf(su); iu = iu * (1.5f - 0.5f * su * iu * iu);
        float iv = rsqrtf(sv); iv = iv * (1.5f - 0.5f * sv * iv * iv);
        float un = u * iu, vn = v * iv;
        xu[idx] = f32_to_bf16_rn(un);
        xi[idx] = f32_to_bf16_rn(vn);
        float d = un - vn;
        asum += d * d;
    }
    #pragma unroll
    for (int m = 1; m < 64; m <<= 1) asum += __shfl_xor(asum, m, 64);
    __shared__ float ws4[4];
    if (lane == 0) ws4[wave] = asum;
    __syncthreads();
    if (threadIdx.x == 0) pa[blockIdx.x] = ws4[0] + ws4[1] + ws4[2] + ws4[3];
}

// ---- kernel 2: 256x256 gram tile + exp + per-block partial -----------------
// Fragment-order LDS layout per 16-row tile: ushort idx =
//   tile*1024 + (c)*128 + r16*8, c = k/8 in 0..7  (2 KB per tile).
// Operand read for (tile, ks): ds_read_b128 at ushort idx
//   tile*1024 + ks*512 + lane*8  -> contiguous 1 KB per wave. Conflict-free.
__global__ void __launch_bounds__(512, 4) gram_exp_kernel(
    const unsigned short* __restrict__ xu,
    const unsigned short* __restrict__ xi,
    float* __restrict__ pg)
{
    const int bx = blockIdx.x, by = blockIdx.y;
    const unsigned short* __restrict__ X;
    int bi, bj;
    if (by < NT2) {
        if (by >= bx) { X = xu; bi = bx; bj = by; }
        else          { X = xi; bi = by; bj = bx; }
    } else            { X = xi; bi = bx; bj = bx; }
    const bool diag = (bi == bj);

    __shared__ unsigned short lds[2][16384];   // [stripe][32 KB], 64 KB total
    __shared__ float wsum[8];

    // ---- stage both 256-row stripes, fragment-order ----
    {
        const int base0 = bi * 256, base1 = bj * 256;
        #pragma unroll
        for (int i = 0; i < 8; ++i) {
            int n = i * 512 + threadIdx.x;       // 16B-chunk id, 0..4095
            int s = n >> 11;                     // stripe
            int m = n & 2047;                    // chunk within stripe
            int r = m >> 3, c = m & 7;
            int gro = ((s ? base1 : base0) + r) * DIM + c * 8;
            bf16x8 v = *reinterpret_cast<const bf16x8*>(X + gro);
            int di = (r >> 4) * 1024 + c * 128 + (r & 15) * 8;
            *reinterpret_cast<bf16x8*>(&lds[s][di]) = v;
        }
    }
    __syncthreads();

    const int wave = threadIdx.x >> 6;
    const int lane = threadIdx.x & 63;

    // A fragments for this wave's 2 row-16-tiles (rows wave*32 .. +32)
    bf16x8 a[2][2];
    #pragma unroll
    for (int rb = 0; rb < 2; ++rb)
        #pragma unroll
        for (int ks = 0; ks < 2; ++ks)
            a[rb][ks] = *reinterpret_cast<const bf16x8*>(
                &lds[0][(wave * 2 + rb) * 1024 + ks * 512 + lane * 8]);

    float l0 = 0.0f, l1 = 0.0f;
    #pragma unroll
    for (int cb = 0; cb < 16; ++cb) {
        bf16x8 b0 = *reinterpret_cast<const bf16x8*>(&lds[1][cb * 1024 + lane * 8]);
        bf16x8 b1 = *reinterpret_cast<const bf16x8*>(&lds[1][cb * 1024 + 512 + lane * 8]);
        #pragma unroll
        for (int rb = 0; rb < 2; ++rb) {
            f32x4 c = {0.f, 0.f, 0.f, 0.f};
            c = __builtin_amdgcn_mfma_f32_16x16x32_bf16(a[rb][0], b0, c, 0, 0, 0);
            c = __builtin_amdgcn_mfma_f32_16x16x32_bf16(a[rb][1], b1, c, 0, 0, 0);
            // exp(-T*max(2-2g,0)) = min(exp2(g*S - S), 1); clamp only needed
            // where g>1 possible (diagonal tiles).
            #pragma unroll
            for (int e = 0; e < 4; ++e) {
                float ex = __builtin_amdgcn_exp2f(fmaf(c[e], EXP_SCALE, -EXP_SCALE));
                if (diag) ex = fminf(ex, 1.0f);
                if (e & 1) l1 += ex; else l0 += ex;
            }
        }
    }

    float local = l0 + l1;
    #pragma unroll
    for (int m = 1; m < 64; m <<= 1) local += __shfl_xor(local, m, 64);
    if (lane == 0) wsum[wave] = local;
    __syncthreads();
    if (threadIdx.x == 0) {
        float t = 0.f;
        #pragma unroll
        for (int w = 0; w < 8; ++w) t += wsum[w];
        pg[by * NT2 + bx] = diag ? t : 2.0f * t;
    }
}

// ---- kernel 3: reduce partials + combine -----------------------------------
__global__ void __launch_bounds__(256) final_kernel(
    const float* __restrict__ pa, const float* __restrict__ pg,
    float* __restrict__ out)
{
    float a = 0.f, su = 0.f, si = 0.f;
    for (int s = threadIdx.x; s < K1_BLOCKS; s += 256) a += pa[s];
    for (int s = threadIdx.x; s < GRAM_SLOTS; s += 256) {
        int bx = s & (NT2 - 1), by = s >> 5;
        bool is_item = (by == NT2) || (by < bx);
        float v = pg[s];
        if (is_item) si += v; else su += v;
    }
    #pragma unroll
    for (int m = 1; m < 64; m <<= 1) {
        a  += __shfl_xor(a,  m, 64);
        su += __shfl_xor(su, m, 64);
        si += __shfl_xor(si, m, 64);
    }
    __shared__ float r[12];
    const int wave = threadIdx.x >> 6, lane = threadIdx.x & 63;
    if (lane == 0) { r[wave] = a; r[4 + wave] = su; r[8 + wave] = si; }
    __syncthreads();
    if (threadIdx.x == 0) {
        float A  = r[0] + r[1] + r[2]  + r[3];
        float SU = r[4] + r[5] + r[6]  + r[7];
        float SI = r[8] + r[9] + r[10] + r[11];
        const float n = (float)NROWS;
        const float denom = n * (n - 1.0f);
        out[0] = A / n + 0.5f * (logf((SU - n) / denom + EPS_F)
                               + logf((SI - n) / denom + EPS_F));
    }
}

extern "C" void kernel_launch(void* const* d_in, const int* in_sizes, int n_in,
                              void* d_out, int out_size, void* d_ws, size_t ws_size,
                              hipStream_t stream)
{
    const float* user = (const float*)d_in[0];
    const float* item = (const float*)d_in[1];

    unsigned short* xu = (unsigned short*)d_ws;                 // 1 MB
    unsigned short* xi = xu + (size_t)NROWS * DIM;              // 1 MB
    float* pa = (float*)(xi + (size_t)NROWS * DIM);             // 512 floats
    float* pg = pa + K1_BLOCKS;                                 // 1056 floats

    normalize_align_kernel<<<K1_BLOCKS, 256, 0, stream>>>(user, item, xu, xi, pa);
    gram_exp_kernel<<<dim3(NT2, NT2 + 1), 512, 0, stream>>>(xu, xi, pg);
    final_kernel<<<1, 256, 0, stream>>>(pa, pg, (float*)d_out);
}

// Round 6
// 83.802 us; speedup vs baseline: 2.7620x; 1.0438x over previous
//
#include <hip/hip_runtime.h>
#include <cstdint>

// DirectAU loss: align(u,i) + 0.5*(uniform(u) + uniform(i)), T=2, GAMMA=1.
// N=8192 rows, D=64.
//   k1: normalize rows (fp32), write bf16 copies to ws, per-block align partial.
//   k2: 256x256-tile X@X^T via mfma_f32_16x16x32_bf16. B-stripe (32 KB) staged
//       to LDS in fragment order (conflict-free ds_read_b128); A-fragments
//       read directly from global before the barrier. 4 blocks/CU -> all 1056
//       blocks co-resident. Fused exp2+sum epilogue, per-block partial.
//       Upper-triangle tiles weight 2; lower-triangle slots serve ITEM matrix;
//       extra grid column = item diagonals.
//   k3: reduce partials + combine -> d_out[0].
// R6: R5 exposed the residual: harness re-poisons the 256 MiB ws with 0xAA
// every iteration (42us @ 80% HBM peak, in the timed path) — also why caches
// are cold each iter. Controllable budget is only our ~25us. This round:
// halve gram LDS (stage B only) -> 4 blocks/CU, one-shot residency.

#define NROWS 8192
#define DIM 64
#define NT2 32                            // 8192/256 tiles per side
#define GRAM_SLOTS (NT2 * (NT2 + 1))      // 32*33 = 1056
#define K1_BLOCKS 512                     // 4 waves/block * 4 rows/wave

static constexpr float EXP_SCALE = 5.770780163555852f; // 2*T*log2(e) = 4*log2(e)
static constexpr float EPS_F = 1e-8f;

typedef __bf16 bf16x8 __attribute__((ext_vector_type(8)));
typedef float f32x4 __attribute__((ext_vector_type(4)));

__device__ __forceinline__ unsigned short f32_to_bf16_rn(float f) {
    union { float f; uint32_t u; } c; c.f = f;
    uint32_t u = c.u;
    uint32_t r = u + 0x7FFFu + ((u >> 16) & 1u);
    return (unsigned short)(r >> 16);
}

// ---- kernel 1: normalize + bf16 cast + per-block alignment partial ---------
__global__ void __launch_bounds__(256) normalize_align_kernel(
    const float* __restrict__ user, const float* __restrict__ item,
    unsigned short* __restrict__ xu, unsigned short* __restrict__ xi,
    float* __restrict__ pa)
{
    const int wave = threadIdx.x >> 6;
    const int lane = threadIdx.x & 63;
    const int wid  = blockIdx.x * 4 + wave;   // 0..2047, 4 rows per wave

    float asum = 0.0f;
    #pragma unroll
    for (int r = 0; r < 4; ++r) {
        const int idx = (wid * 4 + r) * DIM + lane;   // wave spans one row
        float u = user[idx];
        float v = item[idx];
        float su = u * u, sv = v * v;
        #pragma unroll
        for (int m = 1; m < 64; m <<= 1) {
            su += __shfl_xor(su, m, 64);
            sv += __shfl_xor(sv, m, 64);
        }
        float iu = rsqrtf(su); iu = iu * (1.5f - 0.5f * su * iu * iu);
        float iv = rsqrtf(sv); iv = iv * (1.5f - 0.5f * sv * iv * iv);
        float un = u * iu, vn = v * iv;
        xu[idx] = f32_to_bf16_rn(un);
        xi[idx] = f32_to_bf16_rn(vn);
        float d = un - vn;
        asum += d * d;
    }
    #pragma unroll
    for (int m = 1; m < 64; m <<= 1) asum += __shfl_xor(asum, m, 64);
    __shared__ float ws4[4];
    if (lane == 0) ws4[wave] = asum;
    __syncthreads();
    if (threadIdx.x == 0) pa[blockIdx.x] = ws4[0] + ws4[1] + ws4[2] + ws4[3];
}

// ---- kernel 2: 256x256 gram tile + exp + per-block partial -----------------
// B-stripe fragment-order LDS layout per 16-row tile: ushort idx =
//   tile*1024 + c*128 + r16*8  (c = k/8 in 0..7; 2 KB per tile, 32 KB total).
// Operand read for (tile, ks): ds_read_b128 at tile*1024 + ks*512 + lane*8
//   -> contiguous 1 KB per wave, conflict-free (same addr across waves).
__global__ void __launch_bounds__(512, 8) gram_exp_kernel(
    const unsigned short* __restrict__ xu,
    const unsigned short* __restrict__ xi,
    float* __restrict__ pg)
{
    const int bx = blockIdx.x, by = blockIdx.y;
    const unsigned short* __restrict__ X;
    int bi, bj;
    if (by < NT2) {
        if (by >= bx) { X = xu; bi = bx; bj = by; }
        else          { X = xi; bi = by; bj = bx; }
    } else            { X = xi; bi = bx; bj = bx; }
    const bool diag = (bi == bj);

    __shared__ unsigned short lds[16384];      // 32 KB: B-stripe only
    __shared__ float wsum[8];

    const int wave = threadIdx.x >> 6;
    const int lane = threadIdx.x & 63;

    // A fragments straight from global (issued early, overlap staging).
    // rows bi*256 + wave*32 + rb*16 + (lane&15); 16B-aligned bf16x8 chunks.
    bf16x8 a[2][2];
    {
        const int arow = bi * 256 + wave * 32 + (lane & 15);
        const int acol = (lane >> 4) * 8;
        #pragma unroll
        for (int rb = 0; rb < 2; ++rb)
            #pragma unroll
            for (int ks = 0; ks < 2; ++ks)
                a[rb][ks] = *reinterpret_cast<const bf16x8*>(
                    X + (arow + rb * 16) * DIM + acol + ks * 32);
    }

    // Stage B-stripe (rows bj*256..+256), coalesced global -> fragment-order LDS.
    {
        const int base = bj * 256;
        #pragma unroll
        for (int i = 0; i < 4; ++i) {
            int n = i * 512 + threadIdx.x;       // 16B-chunk id, 0..2047
            int r = n >> 3, c = n & 7;
            bf16x8 v = *reinterpret_cast<const bf16x8*>(X + (base + r) * DIM + c * 8);
            int di = (r >> 4) * 1024 + c * 128 + (r & 15) * 8;
            *reinterpret_cast<bf16x8*>(&lds[di]) = v;
        }
    }
    __syncthreads();

    float l0 = 0.0f, l1 = 0.0f;
    #pragma unroll
    for (int cb = 0; cb < 16; ++cb) {
        bf16x8 b0 = *reinterpret_cast<const bf16x8*>(&lds[cb * 1024 + lane * 8]);
        bf16x8 b1 = *reinterpret_cast<const bf16x8*>(&lds[cb * 1024 + 512 + lane * 8]);
        #pragma unroll
        for (int rb = 0; rb < 2; ++rb) {
            f32x4 c = {0.f, 0.f, 0.f, 0.f};
            c = __builtin_amdgcn_mfma_f32_16x16x32_bf16(a[rb][0], b0, c, 0, 0, 0);
            c = __builtin_amdgcn_mfma_f32_16x16x32_bf16(a[rb][1], b1, c, 0, 0, 0);
            // exp(-T*max(2-2g,0)) = min(exp2(g*S - S), 1); clamp only needed
            // where g>1 possible (diagonal tiles).
            #pragma unroll
            for (int e = 0; e < 4; ++e) {
                float ex = __builtin_amdgcn_exp2f(fmaf(c[e], EXP_SCALE, -EXP_SCALE));
                if (diag) ex = fminf(ex, 1.0f);
                if (e & 1) l1 += ex; else l0 += ex;
            }
        }
    }

    float local = l0 + l1;
    #pragma unroll
    for (int m = 1; m < 64; m <<= 1) local += __shfl_xor(local, m, 64);
    if (lane == 0) wsum[wave] = local;
    __syncthreads();
    if (threadIdx.x == 0) {
        float t = 0.f;
        #pragma unroll
        for (int w = 0; w < 8; ++w) t += wsum[w];
        pg[by * NT2 + bx] = diag ? t : 2.0f * t;
    }
}

// ---- kernel 3: reduce partials + combine -----------------------------------
__global__ void __launch_bounds__(256) final_kernel(
    const float* __restrict__ pa, const float* __restrict__ pg,
    float* __restrict__ out)
{
    float a = 0.f, su = 0.f, si = 0.f;
    for (int s = threadIdx.x; s < K1_BLOCKS; s += 256) a += pa[s];
    for (int s = threadIdx.x; s < GRAM_SLOTS; s += 256) {
        int bx = s & (NT2 - 1), by = s >> 5;
        bool is_item = (by == NT2) || (by < bx);
        float v = pg[s];
        if (is_item) si += v; else su += v;
    }
    #pragma unroll
    for (int m = 1; m < 64; m <<= 1) {
        a  += __shfl_xor(a,  m, 64);
        su += __shfl_xor(su, m, 64);
        si += __shfl_xor(si, m, 64);
    }
    __shared__ float r[12];
    const int wave = threadIdx.x >> 6, lane = threadIdx.x & 63;
    if (lane == 0) { r[wave] = a; r[4 + wave] = su; r[8 + wave] = si; }
    __syncthreads();
    if (threadIdx.x == 0) {
        float A  = r[0] + r[1] + r[2]  + r[3];
        float SU = r[4] + r[5] + r[6]  + r[7];
        float SI = r[8] + r[9] + r[10] + r[11];
        const float n = (float)NROWS;
        const float denom = n * (n - 1.0f);
        out[0] = A / n + 0.5f * (logf((SU - n) / denom + EPS_F)
                               + logf((SI - n) / denom + EPS_F));
    }
}

extern "C" void kernel_launch(void* const* d_in, const int* in_sizes, int n_in,
                              void* d_out, int out_size, void* d_ws, size_t ws_size,
                              hipStream_t stream)
{
    const float* user = (const float*)d_in[0];
    const float* item = (const float*)d_in[1];

    unsigned short* xu = (unsigned short*)d_ws;                 // 1 MB
    unsigned short* xi = xu + (size_t)NROWS * DIM;              // 1 MB
    float* pa = (float*)(xi + (size_t)NROWS * DIM);             // 512 floats
    float* pg = pa + K1_BLOCKS;                                 // 1056 floats

    normalize_align_kernel<<<K1_BLOCKS, 256, 0, stream>>>(user, item, xu, xi, pa);
    gram_exp_kernel<<<dim3(NT2, NT2 + 1), 512, 0, stream>>>(xu, xi, pg);
    final_kernel<<<1, 256, 0, stream>>>(pa, pg, (float*)d_out);
}